// Round 8
// baseline (467.845 us; speedup 1.0000x reference)
//
#include <hip/hip_runtime.h>
#include <math.h>

#define C 64
#define D 16
#define EPSF 1e-8f
#define DVAR 0.5f
#define DDIST 1.5f
#define VARSCALE 4294967296.0
#define INV_VARSCALE (1.0 / 4294967296.0)

#define NB 2048         // 8 blocks/CU x 256 CUs
#define NTHR (NB * 256) // 524288 = 1<<19
#define SLICE 1088      // per-block slice: 1024 f32 sums (bit-cast) + 64 int counts

// ws int32 layout (nothing needs pre-zeroing; everything is written before read):
//   [0 .. NB*SLICE)            per-block slices, arr[b][0..1087]
//   [GF0 .. GF0+1088)          reduced sums (f32 bits) [0,1024) + counts (int) [1024,1088)
//   [V0 .. V0+2*NB)            per-block var partials, u64 fixed-point (V0 even -> 8B-aligned)
#define GF0 (NB * SLICE)
#define V0 (GF0 + 1088)

typedef short short8 __attribute__((ext_vector_type(8)));
typedef float f32x4 __attribute__((ext_vector_type(4)));

// f32 -> bf16 bits, round-to-nearest-even (finite inputs)
__device__ __forceinline__ unsigned bf16rn(float f) {
    unsigned u = __float_as_uint(f);
    return (u + 0x7FFFu + ((u >> 16) & 1u)) >> 16;
}

// MFMA one-hot scatter-sum: sums = onehot(labels)^T * features.
// Replaces the LDS-atomic histogram (suspected DS-bank-op-throughput wall:
// 17 RMW bank-ops/point; R5's instr-count halving kept bytes constant -> null).
// Exact-enough: f = h + l with h=bf16rn(f), l=bf16rn(f-h); |f-h-l| <= 2^-16|f|.
// K-slot trick: A and B use the SAME (lane>>4, j) slot mapping, so the result
// is invariant to the hardware's internal K permutation. C/D layout is the
// HW-verified col=lane&15, row=(lane>>4)*4+reg.
__global__ __launch_bounds__(256) void k_sums(const float* __restrict__ feat,
                                              const int* __restrict__ labels, int N,
                                              int* __restrict__ arr) {
    __shared__ float s_wsum[4 * 1024];
    __shared__ unsigned s_cnt[C];
    int t = threadIdx.x, b = blockIdx.x;
    int w = t >> 6, lane = t & 63;
    int g = lane >> 4, r = lane & 15;
    if (t < C) s_cnt[t] = 0u;
    __syncthreads();

    f32x4 acc0 = {0.f, 0.f, 0.f, 0.f}, acc1 = {0.f, 0.f, 0.f, 0.f};
    f32x4 acc2 = {0.f, 0.f, 0.f, 0.f}, acc3 = {0.f, 0.f, 0.f, 0.f};

    int ntiles = (N + 63) >> 6;   // 64 points per block-iteration (16 per wave)
    for (int it = b; it < ntiles; it += NB) {
        int tile = ntiles - 1 - it;              // reverse: end at head so k_hinge hits L3
        int p0 = (tile << 6) + (w << 4);         // this wave's 16 points
        // counts: lanes 0-15 only -> ONE ds-atomic per 16 points (was 17 bank-ops/point)
        if (g == 0) {
            int pc = p0 + r;
            if (pc < N) atomicAdd(&s_cnt[labels[pc] & 63], 1u);
        }
        short8 bfrag;
        short8 a0, a1, a2, a3;
        #pragma unroll
        for (int tt = 0; tt < 4; tt++) {
            int pt = p0 + (g << 2) + tt;         // slot pair (2tt, 2tt+1) = point pt
            bool ok = pt < N;
            int lab = ok ? (labels[pt] & 63) : -1;
            float f = ok ? feat[pt * 16 + r] : 0.0f;   // B column n = r (comp index)
            unsigned hb = bf16rn(f);
            float hf = __uint_as_float(hb << 16);
            unsigned lb = bf16rn(f - hf);              // exact residual, then RNE
            bfrag[2 * tt]     = (short)hb;             // split 0
            bfrag[2 * tt + 1] = (short)lb;             // split 1
            // one-hot A rows m = r for cluster blocks 0/16/32/48 (bf16 1.0 = 0x3F80)
            short e0 = (lab == r)      ? (short)0x3F80 : (short)0;
            short e1 = (lab == r + 16) ? (short)0x3F80 : (short)0;
            short e2 = (lab == r + 32) ? (short)0x3F80 : (short)0;
            short e3 = (lab == r + 48) ? (short)0x3F80 : (short)0;
            a0[2 * tt] = e0; a0[2 * tt + 1] = e0;
            a1[2 * tt] = e1; a1[2 * tt + 1] = e1;
            a2[2 * tt] = e2; a2[2 * tt + 1] = e2;
            a3[2 * tt] = e3; a3[2 * tt + 1] = e3;
        }
        acc0 = __builtin_amdgcn_mfma_f32_16x16x32_bf16(a0, bfrag, acc0, 0, 0, 0);
        acc1 = __builtin_amdgcn_mfma_f32_16x16x32_bf16(a1, bfrag, acc1, 0, 0, 0);
        acc2 = __builtin_amdgcn_mfma_f32_16x16x32_bf16(a2, bfrag, acc2, 0, 0, 0);
        acc3 = __builtin_amdgcn_mfma_f32_16x16x32_bf16(a3, bfrag, acc3, 0, 0, 0);
    }
    // flush: D row = 4g+reg within each 16-cluster block, col = r
    #pragma unroll
    for (int reg = 0; reg < 4; reg++) {
        int row = (g << 2) + reg;
        s_wsum[w * 1024 + (row     ) * 16 + r] = acc0[reg];
        s_wsum[w * 1024 + (row + 16) * 16 + r] = acc1[reg];
        s_wsum[w * 1024 + (row + 32) * 16 + r] = acc2[reg];
        s_wsum[w * 1024 + (row + 48) * 16 + r] = acc3[reg];
    }
    __syncthreads();
    // block reduce 4 waves (fixed order, deterministic) -> private slice
    for (int i = t; i < 1024; i += 256) {
        float s = s_wsum[i] + s_wsum[1024 + i] + s_wsum[2048 + i] + s_wsum[3072 + i];
        arr[b * SLICE + i] = __float_as_int(s);
    }
    if (t < C) arr[b * SLICE + 1024 + t] = (int)s_cnt[t];
}

// Column-reduce the NB x SLICE slice matrix: f32 for sums, int for counts.
__global__ __launch_bounds__(256) void k_reduce(const int* __restrict__ arr,
                                                int* __restrict__ g_final) {
    __shared__ float sf[256];
    __shared__ int si[256];
    int o = blockIdx.x;   // 0..1087
    int t = threadIdx.x;
    if (o < 1024) {
        float part = 0.0f;
        #pragma unroll
        for (int j = 0; j < NB / 256; j++)
            part += __int_as_float(arr[(t + j * 256) * SLICE + o]);
        sf[t] = part;
        __syncthreads();
        for (int st = 128; st > 0; st >>= 1) {
            if (t < st) sf[t] += sf[t + st];
            __syncthreads();
        }
        if (t == 0) g_final[o] = __float_as_int(sf[0]);
    } else {
        int part = 0;
        #pragma unroll
        for (int j = 0; j < NB / 256; j++)
            part += arr[(t + j * 256) * SLICE + o];
        si[t] = part;
        __syncthreads();
        for (int st = 128; st > 0; st >>= 1) {
            if (t < st) si[t] += si[t + st];
            __syncthreads();
        }
        if (t == 0) g_final[o] = si[0];
    }
}

__device__ __forceinline__ float point_term(const float* __restrict__ s_means,
                                            const float* __restrict__ s_w,
                                            float4 a, float4 bb, float4 cc, float4 dd,
                                            int c) {
    const float* m = &s_means[c * 20];
    float4 m0 = *(const float4*)(m + 0);
    float4 m1 = *(const float4*)(m + 4);
    float4 m2 = *(const float4*)(m + 8);
    float4 m3 = *(const float4*)(m + 12);
    float ss = 0.0f, dx;
    dx = a.x - m0.x + EPSF; ss += dx * dx;
    dx = a.y - m0.y + EPSF; ss += dx * dx;
    dx = a.z - m0.z + EPSF; ss += dx * dx;
    dx = a.w - m0.w + EPSF; ss += dx * dx;
    dx = bb.x - m1.x + EPSF; ss += dx * dx;
    dx = bb.y - m1.y + EPSF; ss += dx * dx;
    dx = bb.z - m1.z + EPSF; ss += dx * dx;
    dx = bb.w - m1.w + EPSF; ss += dx * dx;
    dx = cc.x - m2.x + EPSF; ss += dx * dx;
    dx = cc.y - m2.y + EPSF; ss += dx * dx;
    dx = cc.z - m2.z + EPSF; ss += dx * dx;
    dx = cc.w - m2.w + EPSF; ss += dx * dx;
    dx = dd.x - m3.x + EPSF; ss += dx * dx;
    dx = dd.y - m3.y + EPSF; ss += dx * dx;
    dx = dd.z - m3.z + EPSF; ss += dx * dx;
    dx = dd.w - m3.w + EPSF; ss += dx * dx;
    float h = fmaxf(sqrtf(ss) - DVAR, 0.0f);
    return h * h * s_w[c];
}

__global__ __launch_bounds__(256) void k_hinge(const float4* __restrict__ f4,
                                               const int* __restrict__ labels, int N,
                                               const int* __restrict__ g_final,
                                               unsigned long long* __restrict__ g_var) {
    // R5-proven body (41.3 us measured = BW ceiling); plain loads (NT reverted).
    __shared__ __align__(16) float s_means[C * 20];
    __shared__ float s_w[C];
    __shared__ float s_red[256];
    int t = threadIdx.x;
    int b = blockIdx.x;
    for (int i = t; i < C * D; i += 256) {
        int c = i >> 4, d = i & 15;
        float cnt = fmaxf((float)g_final[C * D + c], 1.0f);
        s_means[c * 20 + d] = __int_as_float(g_final[i]) / cnt;
    }
    if (t < C) s_w[t] = 1.0f / (fmaxf((float)g_final[C * D + t], 1.0f) * (float)C);
    __syncthreads();

    int gid = b * 256 + t;
    int rounds = N >> 19;            // NTHR == 1<<19
    int rem = N - (rounds << 19);
    float acc = 0.0f;
    int p = gid;
    for (int r = 0; r + 2 <= rounds; r += 2) {
        int p0 = p, p1 = p + NTHR;
        int c0 = labels[p0] & (C - 1);
        int c1 = labels[p1] & (C - 1);
        float4 a0 = f4[4 * p0 + 0], b0 = f4[4 * p0 + 1],
               e0 = f4[4 * p0 + 2], d0 = f4[4 * p0 + 3];
        float4 a1 = f4[4 * p1 + 0], b1 = f4[4 * p1 + 1],
               e1 = f4[4 * p1 + 2], d1 = f4[4 * p1 + 3];
        acc += point_term(s_means, s_w, a0, b0, e0, d0, c0);
        acc += point_term(s_means, s_w, a1, b1, e1, d1, c1);
        p += 2 * NTHR;
    }
    if (rounds & 1) {
        int c0 = labels[p] & (C - 1);
        float4 a0 = f4[4 * p + 0], b0 = f4[4 * p + 1],
               e0 = f4[4 * p + 2], d0 = f4[4 * p + 3];
        acc += point_term(s_means, s_w, a0, b0, e0, d0, c0);
        p += NTHR;
    }
    if (gid < rem) {
        int c0 = labels[p] & (C - 1);
        float4 a0 = f4[4 * p + 0], b0 = f4[4 * p + 1],
               e0 = f4[4 * p + 2], d0 = f4[4 * p + 3];
        acc += point_term(s_means, s_w, a0, b0, e0, d0, c0);
    }
    s_red[t] = acc;
    __syncthreads();
    for (int s = 128; s > 0; s >>= 1) {
        if (t < s) s_red[t] += s_red[t + s];
        __syncthreads();
    }
    if (t == 0)
        g_var[b] = (unsigned long long)((double)s_red[0] * VARSCALE + 0.5);
}

__global__ __launch_bounds__(256) void k_final(const int* __restrict__ g_final,
                                               const unsigned long long* __restrict__ g_var,
                                               float* __restrict__ out) {
    __shared__ float s_m[C * 17];
    __shared__ float red[256];
    __shared__ unsigned long long red64[256];
    int t = threadIdx.x;
    for (int i = t; i < C * D; i += 256) {
        int c = i >> 4, d = i & 15;
        float cnt = fmaxf((float)g_final[C * D + c], 1.0f);
        s_m[c * 17 + d] = __int_as_float(g_final[i]) / cnt;
    }
    // reduce the NB u64 var partials
    unsigned long long vq = 0ull;
    #pragma unroll
    for (int j = 0; j < NB / 256; j++) vq += g_var[t + j * 256];
    red64[t] = vq;
    __syncthreads();
    for (int s = 128; s > 0; s >>= 1) {
        if (t < s) red64[t] += red64[t + s];
        __syncthreads();
    }
    float var_loss = (float)((double)red64[0] * INV_VARSCALE);
    __syncthreads();

    // dist_loss over ordered pairs i != j
    float ds = 0.0f;
    for (int p = t; p < C * C; p += 256) {
        int i = p >> 6, j = p & 63;
        if (i != j) {
            float ss = 0.0f;
            #pragma unroll
            for (int d = 0; d < D; d++) {
                float df = s_m[i * 17 + d] - s_m[j * 17 + d] + EPSF;
                ss += df * df;
            }
            float h = fmaxf(2.0f * DDIST - sqrtf(ss), 0.0f);
            ds += h * h;
        }
    }
    red[t] = ds;
    __syncthreads();
    for (int s = 128; s > 0; s >>= 1) {
        if (t < s) red[t] += red[t + s];
        __syncthreads();
    }
    float dist_loss = red[0] / (float)(C * (C - 1));
    __syncthreads();

    // reg_loss = mean_c ||m_c + EPS||
    float rg = 0.0f;
    if (t < C) {
        float ss = 0.0f;
        #pragma unroll
        for (int d = 0; d < D; d++) {
            float m = s_m[t * 17 + d] + EPSF;
            ss += m * m;
        }
        rg = sqrtf(ss);
    }
    red[t] = rg;
    __syncthreads();
    for (int s = 128; s > 0; s >>= 1) {
        if (t < s) red[t] += red[t + s];
        __syncthreads();
    }
    float reg_loss = red[0] / (float)C;

    if (t == 0) {
        out[0] = var_loss + dist_loss + 0.001f * reg_loss;
        out[1] = var_loss;
        out[2] = dist_loss;
        out[3] = reg_loss;
    }
}

extern "C" void kernel_launch(void* const* d_in, const int* in_sizes, int n_in,
                              void* d_out, int out_size, void* d_ws, size_t ws_size,
                              hipStream_t stream) {
    const float* features = (const float*)d_in[0];
    const int* labels = (const int*)d_in[1];
    int N = in_sizes[0] / D;

    int* ws = (int*)d_ws;
    int* arr = ws;                                                // NB*1088 words
    int* g_final = ws + GF0;                                      // 1024 f32-bit sums + 64 counts
    unsigned long long* g_var = (unsigned long long*)(ws + V0);   // NB u64 partials
    float* out = (float*)d_out;

    hipLaunchKernelGGL(k_sums, dim3(NB), dim3(256), 0, stream, features, labels, N, arr);
    hipLaunchKernelGGL(k_reduce, dim3(SLICE), dim3(256), 0, stream, arr, g_final);
    hipLaunchKernelGGL(k_hinge, dim3(NB), dim3(256), 0, stream,
                       (const float4*)features, labels, N, g_final, g_var);
    hipLaunchKernelGGL(k_final, dim3(1), dim3(256), 0, stream, g_final, g_var, out);
}